// Round 1
// baseline (47769.464 us; speedup 1.0000x reference)
//
#include <hip/hip_runtime.h>
#include <hip/hip_cooperative_groups.h>

namespace cg = cooperative_groups;

#define B_ 128
#define T_ 256
#define IN_ 256
#define H_ 512
#define G4_ 2048   // 4*H
#define TC_ 32     // time chunk
#define NCHUNK_ 8

// ---- workspace layout (float offsets) ----
static constexpr size_t OFF_XG0 = 0;                                   // B*TC*4H
static constexpr size_t OFF_XG1 = OFF_XG0 + (size_t)B_ * TC_ * G4_;    // B*TC*4H
static constexpr size_t OFF_H0C = OFF_XG1 + (size_t)B_ * TC_ * G4_;    // B*TC*H
static constexpr size_t OFF_HS0 = OFF_H0C + (size_t)B_ * TC_ * H_;     // 2*B*H (ping-pong)
static constexpr size_t OFF_CS0 = OFF_HS0 + 2 * (size_t)B_ * H_;       // B*H
static constexpr size_t OFF_HS1 = OFF_CS0 + (size_t)B_ * H_;           // 2*B*H
static constexpr size_t OFF_CS1 = OFF_HS1 + 2 * (size_t)B_ * H_;       // B*H
static constexpr size_t OFF_END = OFF_CS1 + (size_t)B_ * H_;           // ~19.3M floats = 77MB

// ============================================================================
// GEMM: C[m][n] = sum_k A_row(m)[k] * W[n][k] + bias1[n] + bias2[n]
// A rows are mapped: m -> (b = m>>5, tl = m&31) -> A + (b*T_A + t0 + tl)*K
// (For T_A == TC_, t0 == 0 this is just row m.)  M = B*TC = 4096, N = 2048.
// ============================================================================
__global__ __launch_bounds__(256) void gemm_xg(
    const float* __restrict__ A, const float* __restrict__ W,
    const float* __restrict__ bias1, const float* __restrict__ bias2,
    float* __restrict__ C, int N, int K, int T_A, int t0) {
  __shared__ float As[32][68];  // padded: stride 68 floats (272B, 16B-aligned, bank-rotating)
  __shared__ float Bs[32][68];
  const int tid = threadIdx.x;
  const int m0 = blockIdx.y * 64;
  const int n0 = blockIdx.x * 64;
  const int tx = tid & 15, ty = tid >> 4;
  float acc[4][4] = {};
  for (int k0 = 0; k0 < K; k0 += 32) {
    for (int i = tid; i < 512; i += 256) {
      const int r = i >> 3, k4 = i & 7;
      const int m = m0 + r;
      const int bb = m >> 5, tl = m & 31;
      const float4 a4 = *(const float4*)(A + ((size_t)bb * T_A + t0 + tl) * K + k0 + k4 * 4);
      As[k4 * 4 + 0][r] = a4.x; As[k4 * 4 + 1][r] = a4.y;
      As[k4 * 4 + 2][r] = a4.z; As[k4 * 4 + 3][r] = a4.w;
      const float4 b4 = *(const float4*)(W + (size_t)(n0 + r) * K + k0 + k4 * 4);
      Bs[k4 * 4 + 0][r] = b4.x; Bs[k4 * 4 + 1][r] = b4.y;
      Bs[k4 * 4 + 2][r] = b4.z; Bs[k4 * 4 + 3][r] = b4.w;
    }
    __syncthreads();
#pragma unroll
    for (int k = 0; k < 32; ++k) {
      const float4 av = *(const float4*)&As[k][ty * 4];
      const float4 bv = *(const float4*)&Bs[k][tx * 4];
      const float ar[4] = {av.x, av.y, av.z, av.w};
      const float br[4] = {bv.x, bv.y, bv.z, bv.w};
#pragma unroll
      for (int ii = 0; ii < 4; ++ii)
#pragma unroll
        for (int jj = 0; jj < 4; ++jj)
          acc[ii][jj] = fmaf(ar[ii], br[jj], acc[ii][jj]);
    }
    __syncthreads();
  }
  const int col0 = n0 + tx * 4;
  float bsum[4];
#pragma unroll
  for (int jj = 0; jj < 4; ++jj) bsum[jj] = bias1[col0 + jj] + bias2[col0 + jj];
#pragma unroll
  for (int ii = 0; ii < 4; ++ii) {
    float4 o;
    o.x = acc[ii][0] + bsum[0]; o.y = acc[ii][1] + bsum[1];
    o.z = acc[ii][2] + bsum[2]; o.w = acc[ii][3] + bsum[3];
    *(float4*)(C + (size_t)(m0 + ty * 4 + ii) * N + col0) = o;
  }
}

// ============================================================================
// Cooperative LSTM scan over one time-chunk (TC_ steps), one grid.sync/step.
// Grid 256 blocks x 256 threads. Block tile: 32 batch x 8 n. Thread owns (b,n).
// h ping-pongs between h_state slots by time parity; c lives in a register.
// ============================================================================
#define FMA4(acc, hh, ww)                                       \
  acc.x = fmaf(hh.x, ww.x, acc.x); acc.y = fmaf(hh.y, ww.y, acc.y); \
  acc.z = fmaf(hh.z, ww.z, acc.z); acc.w = fmaf(hh.w, ww.w, acc.w);

__global__ __launch_bounds__(256) void lstm_scan(
    const float* __restrict__ xg, const float* __restrict__ W_hh,
    float* __restrict__ h_state, float* __restrict__ c_state,
    float* __restrict__ h_out, int t0) {
  __shared__ float4 hs4[32 * 128];  // 64KB: h tile [32 rows][128 float4], XOR-swizzled
  cg::grid_group grid = cg::this_grid();
  const int tid = threadIdx.x;
  const int b0 = (blockIdx.x & 3) * 32;
  const int n0 = (blockIdx.x >> 2) * 8;
  const int nl = tid & 7, bl = tid >> 3;
  const int b = b0 + bl, n = n0 + nl;
  const float4* W4 = (const float4*)W_hh;
  const float4* w0 = W4 + (size_t)(0 * H_ + n) * 128;
  const float4* w1 = W4 + (size_t)(1 * H_ + n) * 128;
  const float4* w2 = W4 + (size_t)(2 * H_ + n) * 128;
  const float4* w3 = W4 + (size_t)(3 * H_ + n) * 128;
  float c = c_state[(size_t)b * H_ + n];
  const int sw = bl & 7;
  const float4* hb = hs4 + bl * 128;
  for (int t = t0 + 1; t <= t0 + TC_; ++t) {
    // stage previous h tile (32 rows x 512 floats) into LDS, swizzled
    const float4* hsrc =
        (const float4*)(h_state + (size_t)((t - 1) & 1) * B_ * H_ + (size_t)b0 * H_);
#pragma unroll
    for (int i = 0; i < 16; ++i) {
      const int idx = tid + i * 256;
      const int r = idx >> 7, k4 = idx & 127;
      hs4[r * 128 + (k4 ^ (r & 7))] = hsrc[idx];
    }
    __syncthreads();
    float4 a0 = {0, 0, 0, 0}, a1 = {0, 0, 0, 0}, a2 = {0, 0, 0, 0}, a3 = {0, 0, 0, 0};
#pragma unroll 4
    for (int k4 = 0; k4 < 128; ++k4) {
      const float4 h4 = hb[k4 ^ sw];
      const float4 x0 = w0[k4]; FMA4(a0, h4, x0);
      const float4 x1 = w1[k4]; FMA4(a1, h4, x1);
      const float4 x2 = w2[k4]; FMA4(a2, h4, x2);
      const float4 x3 = w3[k4]; FMA4(a3, h4, x3);
    }
    const int tl = t - 1 - t0;
    const float* xgr = xg + ((size_t)((b << 5) + tl)) * G4_ + n;
    const float gi = a0.x + a0.y + a0.z + a0.w + xgr[0];
    const float gf = a1.x + a1.y + a1.z + a1.w + xgr[512];
    const float gg = a2.x + a2.y + a2.z + a2.w + xgr[1024];
    const float go = a3.x + a3.y + a3.z + a3.w + xgr[1536];
    const float iv = 1.f / (1.f + __expf(-gi));
    const float fv = 1.f / (1.f + __expf(-gf));
    const float gv = tanhf(gg);
    const float ov = 1.f / (1.f + __expf(-go));
    c = fv * c + iv * gv;
    const float h = ov * tanhf(c);
    h_state[(size_t)(t & 1) * B_ * H_ + (size_t)b * H_ + n] = h;
    if (h_out) h_out[((size_t)((b << 5) + tl)) * H_ + n] = h;
    grid.sync();
  }
  c_state[(size_t)b * H_ + n] = c;
}

// ============================================================================
// Final FC (10 classes) + log_softmax. One wave per batch row.
// ============================================================================
__global__ __launch_bounds__(64) void fc_logsoftmax(
    const float* __restrict__ h, const float* __restrict__ Wfc,
    const float* __restrict__ bfc, float* __restrict__ out) {
  const int b = blockIdx.x, lane = threadIdx.x;
  const float4* h4 = (const float4*)(h + (size_t)b * H_);
  const float4 hv0 = h4[lane * 2], hv1 = h4[lane * 2 + 1];
  float logits[10];
#pragma unroll
  for (int cc = 0; cc < 10; ++cc) {
    const float4* w4 = (const float4*)(Wfc + (size_t)cc * H_);
    const float4 w0 = w4[lane * 2], w1 = w4[lane * 2 + 1];
    float v = hv0.x * w0.x + hv0.y * w0.y + hv0.z * w0.z + hv0.w * w0.w +
              hv1.x * w1.x + hv1.y * w1.y + hv1.z * w1.z + hv1.w * w1.w;
#pragma unroll
    for (int off = 32; off; off >>= 1) v += __shfl_xor(v, off);
    logits[cc] = v + bfc[cc];
  }
  float m = logits[0];
#pragma unroll
  for (int cc = 1; cc < 10; ++cc) m = fmaxf(m, logits[cc]);
  float s = 0.f;
#pragma unroll
  for (int cc = 0; cc < 10; ++cc) s += __expf(logits[cc] - m);
  const float lse = m + __logf(s);
  if (lane < 10) out[(size_t)b * 10 + lane] = logits[lane] - lse;
}

// ============================================================================
extern "C" void kernel_launch(void* const* d_in, const int* in_sizes, int n_in,
                              void* d_out, int out_size, void* d_ws, size_t ws_size,
                              hipStream_t stream) {
  const float* x    = (const float*)d_in[0];
  const float* Wih0 = (const float*)d_in[1];
  const float* Whh0 = (const float*)d_in[2];
  const float* bih0 = (const float*)d_in[3];
  const float* bhh0 = (const float*)d_in[4];
  const float* Wih1 = (const float*)d_in[5];
  const float* Whh1 = (const float*)d_in[6];
  const float* bih1 = (const float*)d_in[7];
  const float* bhh1 = (const float*)d_in[8];
  const float* Wfc  = (const float*)d_in[9];
  const float* bfc  = (const float*)d_in[10];

  float* ws  = (float*)d_ws;
  float* xg0 = ws + OFF_XG0;
  float* xg1 = ws + OFF_XG1;
  float* h0c = ws + OFF_H0C;
  float* hs0 = ws + OFF_HS0;
  float* cs0 = ws + OFF_CS0;
  float* hs1 = ws + OFF_HS1;
  float* cs1 = ws + OFF_CS1;

  // zero h/c initial state (h slot0 read at t=1; c read at chunk 0)
  hipMemsetAsync(hs0, 0, (OFF_END - OFF_HS0) * sizeof(float), stream);

  const dim3 ggrid(G4_ / 64, (B_ * TC_) / 64);  // (32, 64)
  for (int ch = 0; ch < NCHUNK_; ++ch) {
    int t0 = ch * TC_;
    // layer 0 input gates for this chunk: rows (b, t0..t0+TC)
    gemm_xg<<<ggrid, 256, 0, stream>>>(x, Wih0, bih0, bhh0, xg0, G4_, IN_, T_, t0);
    {
      const float* xgp = xg0; const float* Wp = Whh0;
      float* hsp = hs0; float* csp = cs0; float* hop = h0c; int t0v = t0;
      void* args[] = {&xgp, &Wp, &hsp, &csp, &hop, &t0v};
      hipLaunchCooperativeKernel((void*)lstm_scan, dim3(256), dim3(256), args, 0, stream);
    }
    // layer 1 input gates from layer-0 h chunk
    gemm_xg<<<ggrid, 256, 0, stream>>>(h0c, Wih1, bih1, bhh1, xg1, G4_, H_, TC_, 0);
    {
      const float* xgp = xg1; const float* Wp = Whh1;
      float* hsp = hs1; float* csp = cs1; float* hop = nullptr; int t0v = t0;
      void* args[] = {&xgp, &Wp, &hsp, &csp, &hop, &t0v};
      hipLaunchCooperativeKernel((void*)lstm_scan, dim3(256), dim3(256), args, 0, stream);
    }
  }
  // final h1 is slot (T & 1) == 0 of hs1
  fc_logsoftmax<<<dim3(B_), 64, 0, stream>>>(hs1, Wfc, bfc, (float*)d_out);
}

// Round 2
// 14843.761 us; speedup vs baseline: 3.2182x; 3.2182x over previous
//
#include <hip/hip_runtime.h>

#define B_ 128
#define T_ 256
#define IN_ 256
#define H_ 512
#define G4_ 2048   // 4*H
#define TC_ 16     // time chunk
#define TC_LOG_ 4
#define NCHUNK_ 16

// ---- workspace layout (float offsets) ----
static constexpr size_t OFF_XG0  = 0;                                  // B*TC*4H = 4,194,304
static constexpr size_t OFF_XG1  = OFF_XG0 + (size_t)B_ * TC_ * G4_;   // 4,194,304
static constexpr size_t OFF_H0C  = OFF_XG1 + (size_t)B_ * TC_ * G4_;   // B*TC*H = 1,048,576
static constexpr size_t OFF_HST0 = OFF_H0C + (size_t)B_ * TC_ * H_;    // B*H
static constexpr size_t OFF_CST0 = OFF_HST0 + (size_t)B_ * H_;
static constexpr size_t OFF_HST1 = OFF_CST0 + (size_t)B_ * H_;
static constexpr size_t OFF_CST1 = OFF_HST1 + (size_t)B_ * H_;
static constexpr size_t OFF_WP0  = OFF_CST1 + (size_t)B_ * H_;         // 2048*512 bf16 = 524,288 floats
static constexpr size_t OFF_WP1  = OFF_WP0 + (size_t)G4_ * H_ / 2;
static constexpr size_t OFF_END  = OFF_WP1 + (size_t)G4_ * H_ / 2;     // ~10.75M floats = 43MB

// bf16 round-to-nearest-even from fp32
__device__ __forceinline__ unsigned int bfr(float f) {
  unsigned int u = __float_as_uint(f);
  return (u + 0x7fffu + ((u >> 16) & 1u)) >> 16;
}
#define BLO(u) __uint_as_float((u) << 16)
#define BHI(u) __uint_as_float((u) & 0xffff0000u)

// ============================================================================
// Pack W_hh (fp32 [2048][512]) -> bf16, layout WP[k4][row] where each 16B
// chunk holds W[row][k4*8 .. k4*8+7]. At step time, lanes (consecutive rows)
// read consecutive 16B chunks -> perfectly coalesced streaming.
// ============================================================================
__global__ __launch_bounds__(256) void pack_whh_bf16(
    const float* __restrict__ W, uint4* __restrict__ WP) {
  const int idx = blockIdx.x * 256 + threadIdx.x;  // 0 .. 2048*64-1
  const int k4 = idx >> 11, row = idx & 2047;
  const float* src = W + (size_t)row * H_ + k4 * 8;
  uint4 o;
  o.x = bfr(src[0]) | (bfr(src[1]) << 16);
  o.y = bfr(src[2]) | (bfr(src[3]) << 16);
  o.z = bfr(src[4]) | (bfr(src[5]) << 16);
  o.w = bfr(src[6]) | (bfr(src[7]) << 16);
  WP[idx] = o;
}

// ============================================================================
// GEMM: C[m][n] = sum_k A_row(m)[k] * W[n][k] + bias1[n] + bias2[n]
// A rows: m -> (b = m>>TC_LOG, tl = m&(TC-1)) -> A + (b*T_A + t0 + tl)*K
// M = B*TC = 2048, N = 2048.
// ============================================================================
__global__ __launch_bounds__(256) void gemm_xg(
    const float* __restrict__ A, const float* __restrict__ W,
    const float* __restrict__ bias1, const float* __restrict__ bias2,
    float* __restrict__ C, int N, int K, int T_A, int t0) {
  __shared__ float As[32][68];
  __shared__ float Bs[32][68];
  const int tid = threadIdx.x;
  const int m0 = blockIdx.y * 64;
  const int n0 = blockIdx.x * 64;
  const int tx = tid & 15, ty = tid >> 4;
  float acc[4][4] = {};
  for (int k0 = 0; k0 < K; k0 += 32) {
    for (int i = tid; i < 512; i += 256) {
      const int r = i >> 3, k4 = i & 7;
      const int m = m0 + r;
      const int bb = m >> TC_LOG_, tl = m & (TC_ - 1);
      const float4 a4 = *(const float4*)(A + ((size_t)bb * T_A + t0 + tl) * K + k0 + k4 * 4);
      As[k4 * 4 + 0][r] = a4.x; As[k4 * 4 + 1][r] = a4.y;
      As[k4 * 4 + 2][r] = a4.z; As[k4 * 4 + 3][r] = a4.w;
      const float4 b4 = *(const float4*)(W + (size_t)(n0 + r) * K + k0 + k4 * 4);
      Bs[k4 * 4 + 0][r] = b4.x; Bs[k4 * 4 + 1][r] = b4.y;
      Bs[k4 * 4 + 2][r] = b4.z; Bs[k4 * 4 + 3][r] = b4.w;
    }
    __syncthreads();
#pragma unroll
    for (int k = 0; k < 32; ++k) {
      const float4 av = *(const float4*)&As[k][ty * 4];
      const float4 bv = *(const float4*)&Bs[k][tx * 4];
      const float ar[4] = {av.x, av.y, av.z, av.w};
      const float br[4] = {bv.x, bv.y, bv.z, bv.w};
#pragma unroll
      for (int ii = 0; ii < 4; ++ii)
#pragma unroll
        for (int jj = 0; jj < 4; ++jj)
          acc[ii][jj] = fmaf(ar[ii], br[jj], acc[ii][jj]);
    }
    __syncthreads();
  }
  const int col0 = n0 + tx * 4;
  float bsum[4];
#pragma unroll
  for (int jj = 0; jj < 4; ++jj) bsum[jj] = bias1[col0 + jj] + bias2[col0 + jj];
#pragma unroll
  for (int ii = 0; ii < 4; ++ii) {
    float4 o;
    o.x = acc[ii][0] + bsum[0]; o.y = acc[ii][1] + bsum[1];
    o.z = acc[ii][2] + bsum[2]; o.w = acc[ii][3] + bsum[3];
    *(float4*)(C + (size_t)(m0 + ty * 4 + ii) * N + col0) = o;
  }
}

// ============================================================================
// Batch-partitioned LSTM scan: one block per batch, thread n owns gate
// column n (rows n, n+512, n+1024, n+1536). c in register, h in LDS (bf16).
// Weights streamed from L2 as packed bf16 (2MB/step/block, L2-resident).
// NO grid sync. One __syncthreads per step.
// ============================================================================
__global__ __launch_bounds__(512) void lstm_scan_bp(
    const float* __restrict__ xg,      // [B][TC][2048] gates incl. biases
    const uint4* __restrict__ WP,      // packed bf16 W_hh
    float* __restrict__ h_state,       // [B][512]
    float* __restrict__ c_state,       // [B][512]
    float* __restrict__ h0c) {         // [B][TC][512] or nullptr
  __shared__ unsigned int hls[2][256];  // h as bf16 pairs, double-buffered
  const int b = blockIdx.x;
  const int n = threadIdx.x;
  float c = c_state[(size_t)b * H_ + n];
  if (n < 256) {
    const float h0 = h_state[(size_t)b * H_ + 2 * n];
    const float h1 = h_state[(size_t)b * H_ + 2 * n + 1];
    hls[0][n] = bfr(h0) | (bfr(h1) << 16);
  }
  __syncthreads();
  const uint4* wi = WP + n;
  const uint4* wf = WP + 512 + n;
  const uint4* wg = WP + 1024 + n;
  const uint4* wo = WP + 1536 + n;
  float hout = 0.f;
  for (int t = 0; t < TC_; ++t) {
    const float* xgr = xg + ((size_t)b * TC_ + t) * G4_ + n;
    float2 aI = {xgr[0],    0.f};
    float2 aF = {xgr[512],  0.f};
    float2 aG = {xgr[1024], 0.f};
    float2 aO = {xgr[1536], 0.f};
    const uint4* hp = (const uint4*)hls[t & 1];
#pragma unroll 8
    for (int k4 = 0; k4 < 64; ++k4) {
      const uint4 h4 = hp[k4];  // broadcast LDS read: 8 h values (bf16)
      const uint4 qi = wi[(size_t)k4 * 2048];
      const uint4 qf = wf[(size_t)k4 * 2048];
      const uint4 qg = wg[(size_t)k4 * 2048];
      const uint4 qo = wo[(size_t)k4 * 2048];
      const float h0 = BLO(h4.x), h1 = BHI(h4.x), h2 = BLO(h4.y), h3 = BHI(h4.y);
      const float h4f = BLO(h4.z), h5 = BHI(h4.z), h6 = BLO(h4.w), h7 = BHI(h4.w);
#define GATE(acc, q)                                                        \
      acc.x = fmaf(BLO(q.x), h0, acc.x); acc.y = fmaf(BHI(q.x), h1, acc.y); \
      acc.x = fmaf(BLO(q.y), h2, acc.x); acc.y = fmaf(BHI(q.y), h3, acc.y); \
      acc.x = fmaf(BLO(q.z), h4f, acc.x); acc.y = fmaf(BHI(q.z), h5, acc.y);\
      acc.x = fmaf(BLO(q.w), h6, acc.x); acc.y = fmaf(BHI(q.w), h7, acc.y);
      GATE(aI, qi) GATE(aF, qf) GATE(aG, qg) GATE(aO, qo)
#undef GATE
    }
    const float gi = aI.x + aI.y;
    const float gf = aF.x + aF.y;
    const float gg = aG.x + aG.y;
    const float go = aO.x + aO.y;
    const float iv = 1.f / (1.f + __expf(-gi));
    const float fv = 1.f / (1.f + __expf(-gf));
    const float gv = tanhf(gg);
    const float ov = 1.f / (1.f + __expf(-go));
    c = fv * c + iv * gv;
    hout = ov * tanhf(c);
    if (h0c) h0c[((size_t)b * TC_ + t) * H_ + n] = hout;
    ((unsigned short*)hls[(t + 1) & 1])[n] = (unsigned short)bfr(hout);
    __syncthreads();
  }
  h_state[(size_t)b * H_ + n] = hout;
  c_state[(size_t)b * H_ + n] = c;
}

// ============================================================================
// Final FC (10 classes) + log_softmax. One wave per batch row.
// ============================================================================
__global__ __launch_bounds__(64) void fc_logsoftmax(
    const float* __restrict__ h, const float* __restrict__ Wfc,
    const float* __restrict__ bfc, float* __restrict__ out) {
  const int b = blockIdx.x, lane = threadIdx.x;
  const float4* h4 = (const float4*)(h + (size_t)b * H_);
  const float4 hv0 = h4[lane * 2], hv1 = h4[lane * 2 + 1];
  float logits[10];
#pragma unroll
  for (int cc = 0; cc < 10; ++cc) {
    const float4* w4 = (const float4*)(Wfc + (size_t)cc * H_);
    const float4 w0 = w4[lane * 2], w1 = w4[lane * 2 + 1];
    float v = hv0.x * w0.x + hv0.y * w0.y + hv0.z * w0.z + hv0.w * w0.w +
              hv1.x * w1.x + hv1.y * w1.y + hv1.z * w1.z + hv1.w * w1.w;
#pragma unroll
    for (int off = 32; off; off >>= 1) v += __shfl_xor(v, off);
    logits[cc] = v + bfc[cc];
  }
  float m = logits[0];
#pragma unroll
  for (int cc = 1; cc < 10; ++cc) m = fmaxf(m, logits[cc]);
  float s = 0.f;
#pragma unroll
  for (int cc = 0; cc < 10; ++cc) s += __expf(logits[cc] - m);
  const float lse = m + __logf(s);
  if (lane < 10) out[(size_t)b * 10 + lane] = logits[lane] - lse;
}

// ============================================================================
extern "C" void kernel_launch(void* const* d_in, const int* in_sizes, int n_in,
                              void* d_out, int out_size, void* d_ws, size_t ws_size,
                              hipStream_t stream) {
  const float* x    = (const float*)d_in[0];
  const float* Wih0 = (const float*)d_in[1];
  const float* Whh0 = (const float*)d_in[2];
  const float* bih0 = (const float*)d_in[3];
  const float* bhh0 = (const float*)d_in[4];
  const float* Wih1 = (const float*)d_in[5];
  const float* Whh1 = (const float*)d_in[6];
  const float* bih1 = (const float*)d_in[7];
  const float* bhh1 = (const float*)d_in[8];
  const float* Wfc  = (const float*)d_in[9];
  const float* bfc  = (const float*)d_in[10];

  float* ws   = (float*)d_ws;
  float* xg0  = ws + OFF_XG0;
  float* xg1  = ws + OFF_XG1;
  float* h0c  = ws + OFF_H0C;
  float* hst0 = ws + OFF_HST0;
  float* cst0 = ws + OFF_CST0;
  float* hst1 = ws + OFF_HST1;
  float* cst1 = ws + OFF_CST1;
  uint4* wp0  = (uint4*)(ws + OFF_WP0);
  uint4* wp1  = (uint4*)(ws + OFF_WP1);

  // pack recurrent weights to bf16 (coalesced layout); zero h/c state
  pack_whh_bf16<<<512, 256, 0, stream>>>(Whh0, wp0);
  pack_whh_bf16<<<512, 256, 0, stream>>>(Whh1, wp1);
  hipMemsetAsync(hst0, 0, 4 * (size_t)B_ * H_ * sizeof(float), stream);

  const dim3 ggrid(G4_ / 64, (B_ * TC_) / 64);  // (32, 32)
  for (int ch = 0; ch < NCHUNK_; ++ch) {
    const int t0 = ch * TC_;
    gemm_xg<<<ggrid, 256, 0, stream>>>(x, Wih0, bih0, bhh0, xg0, G4_, IN_, T_, t0);
    lstm_scan_bp<<<dim3(B_), 512, 0, stream>>>(xg0, wp0, hst0, cst0, h0c);
    gemm_xg<<<ggrid, 256, 0, stream>>>(h0c, Wih1, bih1, bhh1, xg1, G4_, H_, TC_, 0);
    lstm_scan_bp<<<dim3(B_), 512, 0, stream>>>(xg1, wp1, hst1, cst1, nullptr);
  }
  fc_logsoftmax<<<dim3(B_), 64, 0, stream>>>(hst1, Wfc, bfc, (float*)d_out);
}

// Round 4
// 10803.062 us; speedup vs baseline: 4.4218x; 1.3740x over previous
//
#include <hip/hip_runtime.h>

#define B_ 128
#define T_ 256
#define IN_ 256
#define H_ 512
#define G4_ 2048   // 4*H
#define TC_ 32     // time chunk
#define TC_LOG_ 5
#define NCHUNK_ 8

// ---- workspace layout (float offsets) ---- (~52MB total)
static constexpr size_t OFF_XG  = 0;                               // B*TC*4H = 8,388,608 (shared by L0/L1)
static constexpr size_t OFF_H0C = OFF_XG + (size_t)B_ * TC_ * G4_; // B*TC*H = 2,097,152
static constexpr size_t OFF_HB0 = OFF_H0C + (size_t)B_ * TC_ * H_; // 2*B*H ping-pong
static constexpr size_t OFF_HB1 = OFF_HB0 + 2 * (size_t)B_ * H_;   // 2*B*H
static constexpr size_t OFF_C0  = OFF_HB1 + 2 * (size_t)B_ * H_;   // B*H
static constexpr size_t OFF_C1  = OFF_C0 + (size_t)B_ * H_;        // B*H
static constexpr size_t OFF_WP0 = OFF_C1 + (size_t)B_ * H_;        // 2048*512 = 1,048,576
static constexpr size_t OFF_WP1 = OFF_WP0 + (size_t)G4_ * H_;
static constexpr size_t OFF_END = OFF_WP1 + (size_t)G4_ * H_;

#define FMA4(acc, hh, ww)                                           \
  acc.x = fmaf(hh.x, ww.x, acc.x); acc.y = fmaf(hh.y, ww.y, acc.y); \
  acc.z = fmaf(hh.z, ww.z, acc.z); acc.w = fmaf(hh.w, ww.w, acc.w);

// ============================================================================
// Pack W_hh [2048][512] fp32 -> wave-coalesced blocked layout:
// WPK[((ct*4+g)*32 + k4)*32 + (cl*4+kq)] = float4 W[g*512+ct*8+cl][kq*128+k4*4 ..+3]
// At step time, a wave's lanes read 32 consecutive float4s (512B contiguous).
// ============================================================================
__global__ __launch_bounds__(256) void pack_whh(
    const float* __restrict__ W, float4* __restrict__ WPK) {
  const int idx = blockIdx.x * 256 + threadIdx.x;  // 0 .. 262143
  const int p   = idx & 31;
  const int cl  = p >> 2, kq = p & 3;
  const int k4  = (idx >> 5) & 31;
  const int g   = (idx >> 10) & 3;
  const int ct  = idx >> 12;                       // 0..63
  const int row = g * H_ + ct * 8 + cl;
  const int k   = kq * 128 + k4 * 4;
  WPK[idx] = *(const float4*)(W + (size_t)row * H_ + k);
}

// ============================================================================
// GEMM: C[m][n] = sum_k A_row(m)[k] * W[n][k] + bias1[n] + bias2[n]
// A rows: m -> (b = m>>TC_LOG, tl = m&(TC-1)) -> A + (b*T_A + t0 + tl)*K
// ============================================================================
__global__ __launch_bounds__(256) void gemm_xg(
    const float* __restrict__ A, const float* __restrict__ W,
    const float* __restrict__ bias1, const float* __restrict__ bias2,
    float* __restrict__ C, int N, int K, int T_A, int t0) {
  __shared__ float As[32][68];
  __shared__ float Bs[32][68];
  const int tid = threadIdx.x;
  const int m0 = blockIdx.y * 64;
  const int n0 = blockIdx.x * 64;
  const int tx = tid & 15, ty = tid >> 4;
  float acc[4][4] = {};
  for (int k0 = 0; k0 < K; k0 += 32) {
    for (int i = tid; i < 512; i += 256) {
      const int r = i >> 3, k4 = i & 7;
      const int m = m0 + r;
      const int bb = m >> TC_LOG_, tl = m & (TC_ - 1);
      const float4 a4 = *(const float4*)(A + ((size_t)bb * T_A + t0 + tl) * K + k0 + k4 * 4);
      As[k4 * 4 + 0][r] = a4.x; As[k4 * 4 + 1][r] = a4.y;
      As[k4 * 4 + 2][r] = a4.z; As[k4 * 4 + 3][r] = a4.w;
      const float4 b4 = *(const float4*)(W + (size_t)(n0 + r) * K + k0 + k4 * 4);
      Bs[k4 * 4 + 0][r] = b4.x; Bs[k4 * 4 + 1][r] = b4.y;
      Bs[k4 * 4 + 2][r] = b4.z; Bs[k4 * 4 + 3][r] = b4.w;
    }
    __syncthreads();
#pragma unroll
    for (int k = 0; k < 32; ++k) {
      const float4 av = *(const float4*)&As[k][ty * 4];
      const float4 bv = *(const float4*)&Bs[k][tx * 4];
      const float ar[4] = {av.x, av.y, av.z, av.w};
      const float br[4] = {bv.x, bv.y, bv.z, bv.w};
#pragma unroll
      for (int ii = 0; ii < 4; ++ii)
#pragma unroll
        for (int jj = 0; jj < 4; ++jj)
          acc[ii][jj] = fmaf(ar[ii], br[jj], acc[ii][jj]);
    }
    __syncthreads();
  }
  const int col0 = n0 + tx * 4;
  float bsum[4];
#pragma unroll
  for (int jj = 0; jj < 4; ++jj) bsum[jj] = bias1[col0 + jj] + bias2[col0 + jj];
#pragma unroll
  for (int ii = 0; ii < 4; ++ii) {
    float4 o;
    o.x = acc[ii][0] + bsum[0]; o.y = acc[ii][1] + bsum[1];
    o.z = acc[ii][2] + bsum[2]; o.w = acc[ii][3] + bsum[3];
    *(float4*)(C + (size_t)(m0 + ty * 4 + ii) * N + col0) = o;
  }
}

// ============================================================================
// One LSTM time step = one dispatch (coherence via kernel boundary).
// 1024 blocks x 256 threads. Block = (bt 0..15, ct 0..63): 8 batch x 8 col.
// Thread = (bl 0..7, cl 0..7, kq 0..3): K=512 split in quarters.
// Weights from packed WPK (contiguous 512B wave reads, L2/MALL-resident).
// ============================================================================
__global__ __launch_bounds__(256) void lstm_step(
    const float4* __restrict__ WPK,
    const float* __restrict__ xg,      // [B][TC][2048] gates incl. biases
    const float* __restrict__ hprev,   // [B][512]
    float* __restrict__ hnext,         // [B][512]
    float* __restrict__ c_state,       // [B][512]
    float* __restrict__ h0c,           // [B][TC][512] or nullptr
    int tl) {                          // local time in chunk
  __shared__ float hl[8][4][132];      // h tile; (bl*4+kq)*33 f4-stride -> 8 bank-groups
  __shared__ float red[64][4][4];      // k-quarter partials [bc][kq][gate]
  const int bid = blockIdx.x;
  const int bt = bid >> 6;             // 0..15
  const int ct = bid & 63;             // 0..63
  const int tid = threadIdx.x;
  const int bl = tid >> 5;             // 0..7
  const int cl = (tid >> 2) & 7;       // 0..7
  const int kq = tid & 3;              // 0..3
  const int b = bt * 8 + bl;
  const int c = ct * 8 + cl;
  // stage h tile (8 x 512 fp32), coalesced
  const float4* hsrc4 = (const float4*)(hprev + (size_t)bt * 8 * H_);
#pragma unroll
  for (int j = 0; j < 4; ++j) {
    const int idx = tid + j * 256;     // 0..1023
    const int r = idx >> 7, k4i = idx & 127;
    *(float4*)&hl[r][k4i >> 5][(k4i & 31) * 4] = hsrc4[r * 128 + k4i];
  }
  float cc = (kq == 0) ? c_state[(size_t)b * H_ + c] : 0.f;
  __syncthreads();
  const float4* wp = WPK + (size_t)(ct * 4) * 1024 + (cl * 4 + kq);
  const float4* hr = (const float4*)&hl[bl][kq][0];
  float4 a0 = {0,0,0,0}, a1 = {0,0,0,0}, a2 = {0,0,0,0}, a3 = {0,0,0,0};
#pragma unroll 8
  for (int k4 = 0; k4 < 32; ++k4) {
    const float4 h4 = hr[k4];
    const float4 q0 = wp[0 * 1024 + k4 * 32]; FMA4(a0, h4, q0);
    const float4 q1 = wp[1 * 1024 + k4 * 32]; FMA4(a1, h4, q1);
    const float4 q2 = wp[2 * 1024 + k4 * 32]; FMA4(a2, h4, q2);
    const float4 q3 = wp[3 * 1024 + k4 * 32]; FMA4(a3, h4, q3);
  }
  const float s0 = a0.x + a0.y + a0.z + a0.w;
  const float s1 = a1.x + a1.y + a1.z + a1.w;
  const float s2 = a2.x + a2.y + a2.z + a2.w;
  const float s3 = a3.x + a3.y + a3.z + a3.w;
  const int bc = bl * 8 + cl;
  if (kq) { red[bc][kq][0] = s0; red[bc][kq][1] = s1;
            red[bc][kq][2] = s2; red[bc][kq][3] = s3; }
  __syncthreads();
  if (kq == 0) {
    float gi = s0, gf = s1, gg = s2, go = s3;
#pragma unroll
    for (int q = 1; q < 4; ++q) {
      gi += red[bc][q][0]; gf += red[bc][q][1];
      gg += red[bc][q][2]; go += red[bc][q][3];
    }
    const float* xr = xg + ((size_t)b * TC_ + tl) * G4_ + c;
    gi += xr[0]; gf += xr[512]; gg += xr[1024]; go += xr[1536];
    const float iv = 1.f / (1.f + __expf(-gi));
    const float fv = 1.f / (1.f + __expf(-gf));
    const float gv = tanhf(gg);
    const float ov = 1.f / (1.f + __expf(-go));
    cc = fv * cc + iv * gv;
    const float hv = ov * tanhf(cc);
    c_state[(size_t)b * H_ + c] = cc;
    hnext[(size_t)b * H_ + c] = hv;
    if (h0c) h0c[((size_t)b * TC_ + tl) * H_ + c] = hv;
  }
}

// ============================================================================
// Final FC (10 classes) + log_softmax. One wave per batch row.
// ============================================================================
__global__ __launch_bounds__(64) void fc_logsoftmax(
    const float* __restrict__ h, const float* __restrict__ Wfc,
    const float* __restrict__ bfc, float* __restrict__ out) {
  const int b = blockIdx.x, lane = threadIdx.x;
  const float4* h4 = (const float4*)(h + (size_t)b * H_);
  const float4 hv0 = h4[lane * 2], hv1 = h4[lane * 2 + 1];
  float logits[10];
#pragma unroll
  for (int cc = 0; cc < 10; ++cc) {
    const float4* w4 = (const float4*)(Wfc + (size_t)cc * H_);
    const float4 w0 = w4[lane * 2], w1 = w4[lane * 2 + 1];
    float v = hv0.x * w0.x + hv0.y * w0.y + hv0.z * w0.z + hv0.w * w0.w +
              hv1.x * w1.x + hv1.y * w1.y + hv1.z * w1.z + hv1.w * w1.w;
#pragma unroll
    for (int off = 32; off; off >>= 1) v += __shfl_xor(v, off);
    logits[cc] = v + bfc[cc];
  }
  float m = logits[0];
#pragma unroll
  for (int cc = 1; cc < 10; ++cc) m = fmaxf(m, logits[cc]);
  float s = 0.f;
#pragma unroll
  for (int cc = 0; cc < 10; ++cc) s += __expf(logits[cc] - m);
  const float lse = m + __logf(s);
  if (lane < 10) out[(size_t)b * 10 + lane] = logits[lane] - lse;
}

// ============================================================================
extern "C" void kernel_launch(void* const* d_in, const int* in_sizes, int n_in,
                              void* d_out, int out_size, void* d_ws, size_t ws_size,
                              hipStream_t stream) {
  const float* x    = (const float*)d_in[0];
  const float* Wih0 = (const float*)d_in[1];
  const float* Whh0 = (const float*)d_in[2];
  const float* bih0 = (const float*)d_in[3];
  const float* bhh0 = (const float*)d_in[4];
  const float* Wih1 = (const float*)d_in[5];
  const float* Whh1 = (const float*)d_in[6];
  const float* bih1 = (const float*)d_in[7];
  const float* bhh1 = (const float*)d_in[8];
  const float* Wfc  = (const float*)d_in[9];
  const float* bfc  = (const float*)d_in[10];

  float* ws   = (float*)d_ws;
  float* XG   = ws + OFF_XG;
  float* h0c  = ws + OFF_H0C;
  float* hb0  = ws + OFF_HB0;
  float* hb1  = ws + OFF_HB1;
  float* c0   = ws + OFF_C0;
  float* c1   = ws + OFF_C1;
  float4* wp0 = (float4*)(ws + OFF_WP0);
  float4* wp1 = (float4*)(ws + OFF_WP1);

  // zero h ping-pong + c state every launch; pack recurrent weights
  hipMemsetAsync(hb0, 0, (OFF_WP0 - OFF_HB0) * sizeof(float), stream);
  pack_whh<<<1024, 256, 0, stream>>>(Whh0, wp0);
  pack_whh<<<1024, 256, 0, stream>>>(Whh1, wp1);

  const size_t BH = (size_t)B_ * H_;
  const dim3 ggrid(G4_ / 64, (B_ * TC_) / 64);  // (32, 64)
  for (int ch = 0; ch < NCHUNK_; ++ch) {
    const int t0 = ch * TC_;
    gemm_xg<<<ggrid, 256, 0, stream>>>(x, Wih0, bih0, bhh0, XG, G4_, IN_, T_, t0);
    for (int t = 0; t < TC_; ++t) {
      const int sg = t0 + t + 1;  // global step, 1-based
      lstm_step<<<1024, 256, 0, stream>>>(
          wp0, XG, hb0 + ((sg - 1) & 1) * BH, hb0 + (sg & 1) * BH, c0, h0c, t);
    }
    gemm_xg<<<ggrid, 256, 0, stream>>>(h0c, Wih1, bih1, bhh1, XG, G4_, H_, TC_, 0);
    for (int t = 0; t < TC_; ++t) {
      const int sg = t0 + t + 1;
      lstm_step<<<1024, 256, 0, stream>>>(
          wp1, XG, hb1 + ((sg - 1) & 1) * BH, hb1 + (sg & 1) * BH, c1, nullptr, t);
    }
  }
  // T=256 even -> final h1 in slot 0
  fc_logsoftmax<<<dim3(B_), 64, 0, stream>>>(hb1, Wfc, bfc, (float*)d_out);
}

// Round 5
// 10145.309 us; speedup vs baseline: 4.7085x; 1.0648x over previous
//
#include <hip/hip_runtime.h>

#define B_ 128
#define T_ 256
#define IN_ 256
#define H_ 512
#define G4_ 2048   // 4*H
#define TC_ 16     // time chunk
#define TC_LOG_ 4
#define NCHUNK_ 16

// ---- workspace layout (float offsets) ---- (~48MB total)
static constexpr size_t OFF_XG0 = 0;                                 // B*TC*4H = 4,194,304
static constexpr size_t OFF_XG1 = OFF_XG0 + (size_t)B_ * TC_ * G4_;  // 4,194,304
static constexpr size_t OFF_H0C = OFF_XG1 + (size_t)B_ * TC_ * G4_;  // B*TC*H = 1,048,576
static constexpr size_t OFF_HB0 = OFF_H0C + (size_t)B_ * TC_ * H_;   // 2*B*H ping-pong
static constexpr size_t OFF_HB1 = OFF_HB0 + 2 * (size_t)B_ * H_;     // 2*B*H
static constexpr size_t OFF_C0  = OFF_HB1 + 2 * (size_t)B_ * H_;     // B*H
static constexpr size_t OFF_C1  = OFF_C0 + (size_t)B_ * H_;          // B*H
static constexpr size_t OFF_WP0 = OFF_C1 + (size_t)B_ * H_;          // 2048*512
static constexpr size_t OFF_WP1 = OFF_WP0 + (size_t)G4_ * H_;
static constexpr size_t OFF_END = OFF_WP1 + (size_t)G4_ * H_;        // ~11.93M floats

#define FMA4(acc, hh, ww)                                           \
  acc.x = fmaf(hh.x, ww.x, acc.x); acc.y = fmaf(hh.y, ww.y, acc.y); \
  acc.z = fmaf(hh.z, ww.z, acc.z); acc.w = fmaf(hh.w, ww.w, acc.w);

// ============================================================================
// Pack W_hh [2048][512] fp32 -> wave-coalesced blocked layout (as round 3):
// WPK[((ct*4+g)*32 + k4)*32 + (cl*4+kq)] = float4 W[g*512+ct*8+cl][kq*128+k4*4]
// ============================================================================
__global__ __launch_bounds__(256) void pack_whh(
    const float* __restrict__ W, float4* __restrict__ WPK) {
  const int idx = blockIdx.x * 256 + threadIdx.x;  // 0 .. 262143
  const int p   = idx & 31;
  const int cl  = p >> 2, kq = p & 3;
  const int k4  = (idx >> 5) & 31;
  const int g   = (idx >> 10) & 3;
  const int ct  = idx >> 12;                       // 0..63
  const int row = g * H_ + ct * 8 + cl;
  const int k   = kq * 128 + k4 * 4;
  WPK[idx] = *(const float4*)(W + (size_t)row * H_ + k);
}

// ============================================================================
// GEMM: C[m][n] = sum_k A_row(m)[k] * W[n][k] + bias1[n] + bias2[n]
// A rows: m -> (b = m>>TC_LOG, tl = m&(TC-1)) -> A + (b*T_A + t0 + tl)*K
// ============================================================================
__global__ __launch_bounds__(256) void gemm_xg(
    const float* __restrict__ A, const float* __restrict__ W,
    const float* __restrict__ bias1, const float* __restrict__ bias2,
    float* __restrict__ C, int N, int K, int T_A, int t0) {
  __shared__ float As[32][68];
  __shared__ float Bs[32][68];
  const int tid = threadIdx.x;
  const int m0 = blockIdx.y * 64;
  const int n0 = blockIdx.x * 64;
  const int tx = tid & 15, ty = tid >> 4;
  float acc[4][4] = {};
  for (int k0 = 0; k0 < K; k0 += 32) {
    for (int i = tid; i < 512; i += 256) {
      const int r = i >> 3, k4 = i & 7;
      const int m = m0 + r;
      const int bb = m >> TC_LOG_, tl = m & (TC_ - 1);
      const float4 a4 = *(const float4*)(A + ((size_t)bb * T_A + t0 + tl) * K + k0 + k4 * 4);
      As[k4 * 4 + 0][r] = a4.x; As[k4 * 4 + 1][r] = a4.y;
      As[k4 * 4 + 2][r] = a4.z; As[k4 * 4 + 3][r] = a4.w;
      const float4 b4 = *(const float4*)(W + (size_t)(n0 + r) * K + k0 + k4 * 4);
      Bs[k4 * 4 + 0][r] = b4.x; Bs[k4 * 4 + 1][r] = b4.y;
      Bs[k4 * 4 + 2][r] = b4.z; Bs[k4 * 4 + 3][r] = b4.w;
    }
    __syncthreads();
#pragma unroll
    for (int k = 0; k < 32; ++k) {
      const float4 av = *(const float4*)&As[k][ty * 4];
      const float4 bv = *(const float4*)&Bs[k][tx * 4];
      const float ar[4] = {av.x, av.y, av.z, av.w};
      const float br[4] = {bv.x, bv.y, bv.z, bv.w};
#pragma unroll
      for (int ii = 0; ii < 4; ++ii)
#pragma unroll
        for (int jj = 0; jj < 4; ++jj)
          acc[ii][jj] = fmaf(ar[ii], br[jj], acc[ii][jj]);
    }
    __syncthreads();
  }
  const int col0 = n0 + tx * 4;
  float bsum[4];
#pragma unroll
  for (int jj = 0; jj < 4; ++jj) bsum[jj] = bias1[col0 + jj] + bias2[col0 + jj];
#pragma unroll
  for (int ii = 0; ii < 4; ++ii) {
    float4 o;
    o.x = acc[ii][0] + bsum[0]; o.y = acc[ii][1] + bsum[1];
    o.z = acc[ii][2] + bsum[2]; o.w = acc[ii][3] + bsum[3];
    *(float4*)(C + (size_t)(m0 + ty * 4 + ii) * N + col0) = o;
  }
}

// ============================================================================
// Fused 2-layer LSTM step: one dispatch advances L0 by one step AND L1 by one
// step (of the previous chunk) — software pipeline across layers. Blocks
// [0,nL0) take the L0 role, the rest L1. Body identical to verified round-3
// lstm_step: block=(bt 0..15, ct 0..63)=8 batch x 8 col; thread=(bl,cl,kq).
// ============================================================================
__global__ __launch_bounds__(256) void lstm_step2(
    const float4* __restrict__ W0, const float* __restrict__ xg0,
    const float* __restrict__ h0p, float* __restrict__ h0n,
    float* __restrict__ cs0, float* __restrict__ hdump,
    const float4* __restrict__ W1, const float* __restrict__ xg1,
    const float* __restrict__ h1p, float* __restrict__ h1n,
    float* __restrict__ cs1, int tl, int nL0) {
  __shared__ float hl[8][4][132];      // conflict-free: (bl,kq) -> 8 distinct bank-quads
  __shared__ float red[64][4][4];      // k-quarter partials [bc][kq][gate]
  int bid = blockIdx.x;
  const float4* WPK; const float* xg; const float* hprev;
  float* hnext; float* cst; float* h0c;
  if (bid < nL0) {
    WPK = W0; xg = xg0; hprev = h0p; hnext = h0n; cst = cs0; h0c = hdump;
  } else {
    bid -= nL0;
    WPK = W1; xg = xg1; hprev = h1p; hnext = h1n; cst = cs1; h0c = nullptr;
  }
  const int bt = bid >> 6;             // 0..15
  const int ct = bid & 63;             // 0..63
  const int tid = threadIdx.x;
  const int bl = tid >> 5;             // 0..7
  const int cl = (tid >> 2) & 7;       // 0..7
  const int kq = tid & 3;              // 0..3
  const int b = bt * 8 + bl;
  const int c = ct * 8 + cl;
  // stage h tile (8 x 512 fp32), coalesced
  const float4* hsrc4 = (const float4*)(hprev + (size_t)bt * 8 * H_);
#pragma unroll
  for (int j = 0; j < 4; ++j) {
    const int idx = tid + j * 256;     // 0..1023
    const int r = idx >> 7, k4i = idx & 127;
    *(float4*)&hl[r][k4i >> 5][(k4i & 31) * 4] = hsrc4[r * 128 + k4i];
  }
  float cc = (kq == 0) ? cst[(size_t)b * H_ + c] : 0.f;
  __syncthreads();
  const float4* wp = WPK + (size_t)(ct * 4) * 1024 + (cl * 4 + kq);
  const float4* hr = (const float4*)&hl[bl][kq][0];
  float4 a0 = {0,0,0,0}, a1 = {0,0,0,0}, a2 = {0,0,0,0}, a3 = {0,0,0,0};
#pragma unroll 8
  for (int k4 = 0; k4 < 32; ++k4) {
    const float4 h4 = hr[k4];
    const float4 q0 = wp[0 * 1024 + k4 * 32]; FMA4(a0, h4, q0);
    const float4 q1 = wp[1 * 1024 + k4 * 32]; FMA4(a1, h4, q1);
    const float4 q2 = wp[2 * 1024 + k4 * 32]; FMA4(a2, h4, q2);
    const float4 q3 = wp[3 * 1024 + k4 * 32]; FMA4(a3, h4, q3);
  }
  const float s0 = a0.x + a0.y + a0.z + a0.w;
  const float s1 = a1.x + a1.y + a1.z + a1.w;
  const float s2 = a2.x + a2.y + a2.z + a2.w;
  const float s3 = a3.x + a3.y + a3.z + a3.w;
  const int bc = bl * 8 + cl;
  if (kq) { red[bc][kq][0] = s0; red[bc][kq][1] = s1;
            red[bc][kq][2] = s2; red[bc][kq][3] = s3; }
  __syncthreads();
  if (kq == 0) {
    float gi = s0, gf = s1, gg = s2, go = s3;
#pragma unroll
    for (int q = 1; q < 4; ++q) {
      gi += red[bc][q][0]; gf += red[bc][q][1];
      gg += red[bc][q][2]; go += red[bc][q][3];
    }
    const float* xr = xg + ((size_t)b * TC_ + tl) * G4_ + c;
    gi += xr[0]; gf += xr[512]; gg += xr[1024]; go += xr[1536];
    const float iv = 1.f / (1.f + __expf(-gi));
    const float fv = 1.f / (1.f + __expf(-gf));
    const float gv = tanhf(gg);
    const float ov = 1.f / (1.f + __expf(-go));
    cc = fv * cc + iv * gv;
    const float hv = ov * tanhf(cc);
    cst[(size_t)b * H_ + c] = cc;
    hnext[(size_t)b * H_ + c] = hv;
    if (h0c) h0c[((size_t)b * TC_ + tl) * H_ + c] = hv;
  }
}

// ============================================================================
// Final FC (10 classes) + log_softmax. One wave per batch row.
// ============================================================================
__global__ __launch_bounds__(64) void fc_logsoftmax(
    const float* __restrict__ h, const float* __restrict__ Wfc,
    const float* __restrict__ bfc, float* __restrict__ out) {
  const int b = blockIdx.x, lane = threadIdx.x;
  const float4* h4 = (const float4*)(h + (size_t)b * H_);
  const float4 hv0 = h4[lane * 2], hv1 = h4[lane * 2 + 1];
  float logits[10];
#pragma unroll
  for (int cc = 0; cc < 10; ++cc) {
    const float4* w4 = (const float4*)(Wfc + (size_t)cc * H_);
    const float4 w0 = w4[lane * 2], w1 = w4[lane * 2 + 1];
    float v = hv0.x * w0.x + hv0.y * w0.y + hv0.z * w0.z + hv0.w * w0.w +
              hv1.x * w1.x + hv1.y * w1.y + hv1.z * w1.z + hv1.w * w1.w;
#pragma unroll
    for (int off = 32; off; off >>= 1) v += __shfl_xor(v, off);
    logits[cc] = v + bfc[cc];
  }
  float m = logits[0];
#pragma unroll
  for (int cc = 1; cc < 10; ++cc) m = fmaxf(m, logits[cc]);
  float s = 0.f;
#pragma unroll
  for (int cc = 0; cc < 10; ++cc) s += __expf(logits[cc] - m);
  const float lse = m + __logf(s);
  if (lane < 10) out[(size_t)b * 10 + lane] = logits[lane] - lse;
}

// ============================================================================
extern "C" void kernel_launch(void* const* d_in, const int* in_sizes, int n_in,
                              void* d_out, int out_size, void* d_ws, size_t ws_size,
                              hipStream_t stream) {
  const float* x    = (const float*)d_in[0];
  const float* Wih0 = (const float*)d_in[1];
  const float* Whh0 = (const float*)d_in[2];
  const float* bih0 = (const float*)d_in[3];
  const float* bhh0 = (const float*)d_in[4];
  const float* Wih1 = (const float*)d_in[5];
  const float* Whh1 = (const float*)d_in[6];
  const float* bih1 = (const float*)d_in[7];
  const float* bhh1 = (const float*)d_in[8];
  const float* Wfc  = (const float*)d_in[9];
  const float* bfc  = (const float*)d_in[10];

  float* ws   = (float*)d_ws;
  float* XG0  = ws + OFF_XG0;
  float* XG1  = ws + OFF_XG1;
  float* h0c  = ws + OFF_H0C;
  float* hb0  = ws + OFF_HB0;
  float* hb1  = ws + OFF_HB1;
  float* c0   = ws + OFF_C0;
  float* c1   = ws + OFF_C1;
  float4* wp0 = (float4*)(ws + OFF_WP0);
  float4* wp1 = (float4*)(ws + OFF_WP1);

  // zero h ping-pong + c state every launch; pack recurrent weights
  hipMemsetAsync(hb0, 0, (OFF_WP0 - OFF_HB0) * sizeof(float), stream);
  pack_whh<<<1024, 256, 0, stream>>>(Whh0, wp0);
  pack_whh<<<1024, 256, 0, stream>>>(Whh1, wp1);

  const size_t BH = (size_t)B_ * H_;
  const dim3 ggrid(G4_ / 64, (B_ * TC_) / 64);  // (32, 32)
  for (int ch = 0; ch < NCHUNK_; ++ch) {
    const int t0 = ch * TC_;
    gemm_xg<<<ggrid, 256, 0, stream>>>(x, Wih0, bih0, bhh0, XG0, G4_, IN_, T_, t0);
    if (ch > 0)
      gemm_xg<<<ggrid, 256, 0, stream>>>(h0c, Wih1, bih1, bhh1, XG1, G4_, H_, TC_, 0);
    for (int t = 0; t < TC_; ++t) {
      const int sg0 = t0 + t + 1;        // L0 global step (1-based)
      const int sg1 = sg0 - TC_;         // L1 global step (prev chunk)
      if (ch == 0) {
        lstm_step2<<<1024, 256, 0, stream>>>(
            wp0, XG0, hb0 + ((sg0 - 1) & 1) * BH, hb0 + (sg0 & 1) * BH, c0, h0c,
            (const float4*)nullptr, (const float*)nullptr,
            (const float*)nullptr, (float*)nullptr, (float*)nullptr, t, 1024);
      } else {
        lstm_step2<<<2048, 256, 0, stream>>>(
            wp0, XG0, hb0 + ((sg0 - 1) & 1) * BH, hb0 + (sg0 & 1) * BH, c0, h0c,
            wp1, XG1, hb1 + ((sg1 - 1) & 1) * BH, hb1 + (sg1 & 1) * BH, c1, t, 1024);
      }
    }
  }
  // pipeline drain: L1 over the last chunk
  gemm_xg<<<ggrid, 256, 0, stream>>>(h0c, Wih1, bih1, bhh1, XG1, G4_, H_, TC_, 0);
  for (int t = 0; t < TC_; ++t) {
    const int sg1 = (NCHUNK_ - 1) * TC_ + t + 1;
    lstm_step2<<<1024, 256, 0, stream>>>(
        (const float4*)nullptr, (const float*)nullptr,
        (const float*)nullptr, (float*)nullptr, (float*)nullptr, (float*)nullptr,
        wp1, XG1, hb1 + ((sg1 - 1) & 1) * BH, hb1 + (sg1 & 1) * BH, c1, t, 0);
  }
  // T=256 even -> final h1 in slot 0
  fc_logsoftmax<<<dim3(B_), 64, 0, stream>>>(hb1, Wfc, bfc, (float*)d_out);
}

// Round 6
// 5627.888 us; speedup vs baseline: 8.4880x; 1.8027x over previous
//
#include <hip/hip_runtime.h>

#define B_ 128
#define T_ 256
#define IN_ 256
#define H_ 512
#define G4_ 2048   // 4*H
#define TC_ 16     // time chunk
#define TC_LOG_ 4
#define NCHUNK_ 16

// ---- workspace layout (float offsets) ---- (~48MB total)
static constexpr size_t OFF_XG0 = 0;                                 // B*TC*4H
static constexpr size_t OFF_XG1 = OFF_XG0 + (size_t)B_ * TC_ * G4_;
static constexpr size_t OFF_H0C = OFF_XG1 + (size_t)B_ * TC_ * G4_;  // B*TC*H
static constexpr size_t OFF_HB0 = OFF_H0C + (size_t)B_ * TC_ * H_;   // 2*B*H ping-pong
static constexpr size_t OFF_HB1 = OFF_HB0 + 2 * (size_t)B_ * H_;
static constexpr size_t OFF_C0  = OFF_HB1 + 2 * (size_t)B_ * H_;
static constexpr size_t OFF_C1  = OFF_C0 + (size_t)B_ * H_;
static constexpr size_t OFF_WP0 = OFF_C1 + (size_t)B_ * H_;          // 2048*512
static constexpr size_t OFF_WP1 = OFF_WP0 + (size_t)G4_ * H_;
static constexpr size_t OFF_END = OFF_WP1 + (size_t)G4_ * H_;

// ============================================================================
// Pack W_hh [2048][512] fp32 -> WPK2[ct(32)][k4(128)][g(4)][cl4(16)] float4,
// element = W[g*512 + ct*16 + cl4][k4*4 .. +3].
// Step-time read: lanes(cl4) x gate g -> 256B contiguous runs; bt4 lanes merge.
// ============================================================================
__global__ __launch_bounds__(256) void pack_whh2(
    const float* __restrict__ W, float4* __restrict__ WPK) {
  const int idx = blockIdx.x * 256 + threadIdx.x;  // 0 .. 262143
  const int cl4 = idx & 15;
  const int g   = (idx >> 4) & 3;
  const int k4  = (idx >> 6) & 127;
  const int ct  = idx >> 13;                       // 0..31
  const int row = g * H_ + ct * 16 + cl4;
  WPK[idx] = *(const float4*)(W + (size_t)row * H_ + k4 * 4);
}

// ============================================================================
// GEMM: C[m][n] = sum_k A_row(m)[k] * W[n][k] + bias1[n] + bias2[n]
// ============================================================================
__global__ __launch_bounds__(256) void gemm_xg(
    const float* __restrict__ A, const float* __restrict__ W,
    const float* __restrict__ bias1, const float* __restrict__ bias2,
    float* __restrict__ C, int N, int K, int T_A, int t0) {
  __shared__ float As[32][68];
  __shared__ float Bs[32][68];
  const int tid = threadIdx.x;
  const int m0 = blockIdx.y * 64;
  const int n0 = blockIdx.x * 64;
  const int tx = tid & 15, ty = tid >> 4;
  float acc[4][4] = {};
  for (int k0 = 0; k0 < K; k0 += 32) {
    for (int i = tid; i < 512; i += 256) {
      const int r = i >> 3, k4 = i & 7;
      const int m = m0 + r;
      const int bb = m >> TC_LOG_, tl = m & (TC_ - 1);
      const float4 a4 = *(const float4*)(A + ((size_t)bb * T_A + t0 + tl) * K + k0 + k4 * 4);
      As[k4 * 4 + 0][r] = a4.x; As[k4 * 4 + 1][r] = a4.y;
      As[k4 * 4 + 2][r] = a4.z; As[k4 * 4 + 3][r] = a4.w;
      const float4 b4 = *(const float4*)(W + (size_t)(n0 + r) * K + k0 + k4 * 4);
      Bs[k4 * 4 + 0][r] = b4.x; Bs[k4 * 4 + 1][r] = b4.y;
      Bs[k4 * 4 + 2][r] = b4.z; Bs[k4 * 4 + 3][r] = b4.w;
    }
    __syncthreads();
#pragma unroll
    for (int k = 0; k < 32; ++k) {
      const float4 av = *(const float4*)&As[k][ty * 4];
      const float4 bv = *(const float4*)&Bs[k][tx * 4];
      const float ar[4] = {av.x, av.y, av.z, av.w};
      const float br[4] = {bv.x, bv.y, bv.z, bv.w};
#pragma unroll
      for (int ii = 0; ii < 4; ++ii)
#pragma unroll
        for (int jj = 0; jj < 4; ++jj)
          acc[ii][jj] = fmaf(ar[ii], br[jj], acc[ii][jj]);
    }
    __syncthreads();
  }
  const int col0 = n0 + tx * 4;
  float bsum[4];
#pragma unroll
  for (int jj = 0; jj < 4; ++jj) bsum[jj] = bias1[col0 + jj] + bias2[col0 + jj];
#pragma unroll
  for (int ii = 0; ii < 4; ++ii) {
    float4 o;
    o.x = acc[ii][0] + bsum[0]; o.y = acc[ii][1] + bsum[1];
    o.z = acc[ii][2] + bsum[2]; o.w = acc[ii][3] + bsum[3];
    *(float4*)(C + (size_t)(m0 + ty * 4 + ii) * N + col0) = o;
  }
}

// ============================================================================
// Fused 2-layer LSTM step, weight-redundancy-minimized.
// mode 0: 256 blocks (both layers). mode 1: 128 blocks L0. mode 2: 128 L1.
// Block: (xcd=bid&7, li=bid>>3) -> layer, bt(0..3: 32 batches), ct = xcd*4 +
// ctl (0..31: 16 hcols). XCD-clustered: each XCD reuses 8 weight slices (1MB).
// Thread (bt4 0..7, cl4 0..15, kh 0..1): 4 batches x 1 hcol x 4 gates x 256 k.
// ============================================================================
#define DOT4(dst, wv, hv)                 \
  dst = fmaf(wv.x, hv.x, dst); dst = fmaf(wv.y, hv.y, dst); \
  dst = fmaf(wv.z, hv.z, dst); dst = fmaf(wv.w, hv.w, dst);

__global__ __launch_bounds__(256) void lstm_step2(
    const float4* __restrict__ W0, const float* __restrict__ xg0,
    const float* __restrict__ h0p, float* __restrict__ h0n,
    float* __restrict__ cs0, float* __restrict__ hdump,
    const float4* __restrict__ W1, const float* __restrict__ xg1,
    const float* __restrict__ h1p, float* __restrict__ h1n,
    float* __restrict__ cs1, int tl, int mode) {
  __shared__ float4 hl4[32 * 128];   // 64KB h tile, col-swizzled by (row>>2)
  __shared__ float4 red4[128 * 5];   // kh=1 partials, pad-5 (bank spread)
  const int bid = blockIdx.x;
  const int xcd = bid & 7;
  int li = bid >> 3;
  int layer;
  if (mode == 0) { layer = li >> 4; li &= 15; } else { layer = mode - 1; }
  const int bt  = li & 3;
  const int ctl = (li >> 2) & 3;
  const int ct  = xcd * 4 + ctl;

  const float4* WPK; const float* xg; const float* hprev;
  float* hnext; float* cst; float* hdmp;
  if (layer == 0) { WPK = W0; xg = xg0; hprev = h0p; hnext = h0n; cst = cs0; hdmp = hdump; }
  else            { WPK = W1; xg = xg1; hprev = h1p; hnext = h1n; cst = cs1; hdmp = nullptr; }

  const int tid = threadIdx.x;
  const int bt4 = tid & 7;
  const int cl4 = (tid >> 3) & 15;
  const int kh  = tid >> 7;
  const int b0  = bt * 32;
  const int hcol = ct * 16 + cl4;

  // prefetch c (kh==0 lanes) while staging h
  float cc[4];
  if (kh == 0) {
#pragma unroll
    for (int i = 0; i < 4; ++i)
      cc[i] = cst[(size_t)(b0 + bt4 * 4 + i) * H_ + hcol];
  }
  // stage h tile: 32 rows x 128 float4, swizzled col' = k4 ^ (row>>2)
  const float4* hsrc = (const float4*)hprev + (size_t)b0 * 128;
#pragma unroll
  for (int j = 0; j < 16; ++j) {
    const int idx = tid + j * 256;   // 0..4095
    const int r = idx >> 7, k4 = idx & 127;
    hl4[r * 128 + (k4 ^ (r >> 2))] = hsrc[idx];
  }
  __syncthreads();

  // 16 register accumulators: a[gate][batch]
  float a[4][4] = {};
  const float4* hb = hl4 + (size_t)(bt4 * 4) * 128;
  const float4* wp = WPK + ((size_t)ct * 128 + kh * 64) * 64 + cl4;
#pragma unroll 4
  for (int k = 0; k < 64; ++k) {
    const int kx = (kh * 64 + k) ^ bt4;
    const float4 h0 = hb[0 * 128 + kx];
    const float4 h1 = hb[1 * 128 + kx];
    const float4 h2 = hb[2 * 128 + kx];
    const float4 h3 = hb[3 * 128 + kx];
    const float4 w0 = wp[k * 64 + 0];
    const float4 w1 = wp[k * 64 + 16];
    const float4 w2 = wp[k * 64 + 32];
    const float4 w3 = wp[k * 64 + 48];
    DOT4(a[0][0], w0, h0) DOT4(a[0][1], w0, h1) DOT4(a[0][2], w0, h2) DOT4(a[0][3], w0, h3)
    DOT4(a[1][0], w1, h0) DOT4(a[1][1], w1, h1) DOT4(a[1][2], w1, h2) DOT4(a[1][3], w1, h3)
    DOT4(a[2][0], w2, h0) DOT4(a[2][1], w2, h1) DOT4(a[2][2], w2, h2) DOT4(a[2][3], w2, h3)
    DOT4(a[3][0], w3, h0) DOT4(a[3][1], w3, h1) DOT4(a[3][2], w3, h2) DOT4(a[3][3], w3, h3)
  }
  // kh=1 writes partials; kh=0 reduces + activations + stores
  const int pair = cl4 * 8 + bt4;
  if (kh) {
#pragma unroll
    for (int g = 0; g < 4; ++g) {
      float4 v; v.x = a[g][0]; v.y = a[g][1]; v.z = a[g][2]; v.w = a[g][3];
      red4[pair * 5 + g] = v;
    }
  }
  __syncthreads();
  if (kh == 0) {
#pragma unroll
    for (int g = 0; g < 4; ++g) {
      const float4 v = red4[pair * 5 + g];
      a[g][0] += v.x; a[g][1] += v.y; a[g][2] += v.z; a[g][3] += v.w;
    }
#pragma unroll
    for (int i = 0; i < 4; ++i) {
      const int b = b0 + bt4 * 4 + i;
      const float* xr = xg + ((size_t)b * TC_ + tl) * G4_ + hcol;
      const float gi = a[0][i] + xr[0];
      const float gf = a[1][i] + xr[512];
      const float gg = a[2][i] + xr[1024];
      const float go = a[3][i] + xr[1536];
      const float iv = 1.f / (1.f + __expf(-gi));
      const float fv = 1.f / (1.f + __expf(-gf));
      const float gv = tanhf(gg);
      const float ov = 1.f / (1.f + __expf(-go));
      const float cn = fv * cc[i] + iv * gv;
      const float hv = ov * tanhf(cn);
      cst[(size_t)b * H_ + hcol] = cn;
      hnext[(size_t)b * H_ + hcol] = hv;
      if (hdmp) hdmp[((size_t)b * TC_ + tl) * H_ + hcol] = hv;
    }
  }
}

// ============================================================================
// Final FC (10 classes) + log_softmax. One wave per batch row.
// ============================================================================
__global__ __launch_bounds__(64) void fc_logsoftmax(
    const float* __restrict__ h, const float* __restrict__ Wfc,
    const float* __restrict__ bfc, float* __restrict__ out) {
  const int b = blockIdx.x, lane = threadIdx.x;
  const float4* h4 = (const float4*)(h + (size_t)b * H_);
  const float4 hv0 = h4[lane * 2], hv1 = h4[lane * 2 + 1];
  float logits[10];
#pragma unroll
  for (int cc = 0; cc < 10; ++cc) {
    const float4* w4 = (const float4*)(Wfc + (size_t)cc * H_);
    const float4 w0 = w4[lane * 2], w1 = w4[lane * 2 + 1];
    float v = hv0.x * w0.x + hv0.y * w0.y + hv0.z * w0.z + hv0.w * w0.w +
              hv1.x * w1.x + hv1.y * w1.y + hv1.z * w1.z + hv1.w * w1.w;
#pragma unroll
    for (int off = 32; off; off >>= 1) v += __shfl_xor(v, off);
    logits[cc] = v + bfc[cc];
  }
  float m = logits[0];
#pragma unroll
  for (int cc = 1; cc < 10; ++cc) m = fmaxf(m, logits[cc]);
  float s = 0.f;
#pragma unroll
  for (int cc = 0; cc < 10; ++cc) s += __expf(logits[cc] - m);
  const float lse = m + __logf(s);
  if (lane < 10) out[(size_t)b * 10 + lane] = logits[lane] - lse;
}

// ============================================================================
extern "C" void kernel_launch(void* const* d_in, const int* in_sizes, int n_in,
                              void* d_out, int out_size, void* d_ws, size_t ws_size,
                              hipStream_t stream) {
  const float* x    = (const float*)d_in[0];
  const float* Wih0 = (const float*)d_in[1];
  const float* Whh0 = (const float*)d_in[2];
  const float* bih0 = (const float*)d_in[3];
  const float* bhh0 = (const float*)d_in[4];
  const float* Wih1 = (const float*)d_in[5];
  const float* Whh1 = (const float*)d_in[6];
  const float* bih1 = (const float*)d_in[7];
  const float* bhh1 = (const float*)d_in[8];
  const float* Wfc  = (const float*)d_in[9];
  const float* bfc  = (const float*)d_in[10];

  float* ws   = (float*)d_ws;
  float* XG0  = ws + OFF_XG0;
  float* XG1  = ws + OFF_XG1;
  float* h0c  = ws + OFF_H0C;
  float* hb0  = ws + OFF_HB0;
  float* hb1  = ws + OFF_HB1;
  float* c0   = ws + OFF_C0;
  float* c1   = ws + OFF_C1;
  float4* wp0 = (float4*)(ws + OFF_WP0);
  float4* wp1 = (float4*)(ws + OFF_WP1);

  // zero h ping-pong + c state every launch; pack recurrent weights
  hipMemsetAsync(hb0, 0, (OFF_WP0 - OFF_HB0) * sizeof(float), stream);
  pack_whh2<<<1024, 256, 0, stream>>>(Whh0, wp0);
  pack_whh2<<<1024, 256, 0, stream>>>(Whh1, wp1);

  const size_t BH = (size_t)B_ * H_;
  const dim3 ggrid(G4_ / 64, (B_ * TC_) / 64);  // (32, 32)
  for (int ch = 0; ch < NCHUNK_; ++ch) {
    const int t0 = ch * TC_;
    gemm_xg<<<ggrid, 256, 0, stream>>>(x, Wih0, bih0, bhh0, XG0, G4_, IN_, T_, t0);
    if (ch > 0)
      gemm_xg<<<ggrid, 256, 0, stream>>>(h0c, Wih1, bih1, bhh1, XG1, G4_, H_, TC_, 0);
    for (int t = 0; t < TC_; ++t) {
      const int sg0 = t0 + t + 1;        // L0 global step (1-based)
      const int sg1 = sg0 - TC_;         // L1 global step (prev chunk)
      const int mode = (ch == 0) ? 1 : 0;
      const int nblk = (ch == 0) ? 128 : 256;
      lstm_step2<<<nblk, 256, 0, stream>>>(
          wp0, XG0, hb0 + ((sg0 - 1) & 1) * BH, hb0 + (sg0 & 1) * BH, c0, h0c,
          wp1, XG1, hb1 + (((sg1 - 1) & 1)) * BH, hb1 + ((sg1 & 1)) * BH, c1,
          t, mode);
    }
  }
  // pipeline drain: L1 over the last chunk
  gemm_xg<<<ggrid, 256, 0, stream>>>(h0c, Wih1, bih1, bhh1, XG1, G4_, H_, TC_, 0);
  for (int t = 0; t < TC_; ++t) {
    const int sg1 = (NCHUNK_ - 1) * TC_ + t + 1;
    lstm_step2<<<128, 256, 0, stream>>>(
        wp0, XG0, hb0, hb0, c0, h0c,
        wp1, XG1, hb1 + ((sg1 - 1) & 1) * BH, hb1 + (sg1 & 1) * BH, c1,
        t, 2);
  }
  // T=256 even -> final h1 in slot 0
  fc_logsoftmax<<<dim3(B_), 64, 0, stream>>>(hb1, Wfc, bfc, (float*)d_out);
}